// Round 4
// baseline (1121.542 us; speedup 1.0000x reference)
//
#include <hip/hip_runtime.h>
#include <hip/hip_bf16.h>

// AFNO spectral block. Round 6: bank-conflict-free FFT phases.
// Pipeline: prep_w -> fwd2d -> gemm_fused -> inv2d
//
// buf1: fp32 float2 spectrum [bc=4096][m=8320], m = v*128 + h  (272.6 MB)
// Wpack: bf16 [2 layers][4 groups][n=256][k=256]; twg (64 f2) after it.
//
// k_fwd2d / k_inv2d: one block per (b,c) image, 512 threads, 64 KB LDS tile
//   [64 rows][128 cols] float2 with XOR swizzle IDX(r,c)=r*128+(c^(r&15)).
//   Bank-pair of a float2 = (c ^ (r&15)) mod 16; wave64 b64 is conflict-free
//   iff <=4 lanes/bank-pair. All phases are remapped so each wave spreads
//   either c mod 16 or r mod 16 across its low lanes:
//   - FFT stages: wave covers 16 rows x 4 butterflies (was 1 row x 64).
//   - inv load: 4 consecutive k per thread (32B global, bitrev LDS spread).
//   - inv transpose: hp&15 from lane&15, j low bits from lane bits 4..5.
//   - inv store: natural (hp, w=lane) read + 2 scalar coalesced stores.

#define NB    8
#define NC    512
#define NG    4
#define ND    128
#define NH    128
#define NW    128
#define NWF   65
#define NM    (NWF * NH)        // 8320
#define INV_N 0.0078125f        // 1/128

typedef unsigned short ushortT;
typedef __bf16 bf16x8 __attribute__((ext_vector_type(8)));
typedef float f32x4 __attribute__((ext_vector_type(4)));

__device__ __forceinline__ ushortT f2b(float f) {
    __hip_bfloat16 h = __float2bfloat16(f);
    return __builtin_bit_cast(ushortT, h);
}

// involution permutation for o1's k ordering (store-side packs contiguous k')
__device__ __forceinline__ int sigma(int n) {
    return ((n & 15) << 4) | ((n >> 4) & 7) | ((n & 128) >> 4);
}

__device__ __forceinline__ int bitrev7(int x) {
    return (int)(__brev((unsigned)x) >> 25);
}

// LDS tile index: row r in [0,64), col c in [0,128).
__device__ __forceinline__ int IDX(int r, int c) {
    return (r << 7) + (c ^ (r & 15));
}

// 64 rows x 128-pt DIT FFT over the col index. Input bitrev order, output
// natural. 512 threads, 8 butterflies/thread/stage. Wave covers 16 rows x
// 4 butterflies -> with the XOR swizzle every access is <=4 lanes/bank-pair.
__device__ __forceinline__ void fft64x128(float2* D, const float2* __restrict__ twg,
                                          int tid, bool inv) {
    for (int s = 0; s < 7; s++) {
        const int hf = 1 << s;
        float2 xl[8], xh[8], w8[8];
        int i0[8], i1[8];
#pragma unroll
        for (int t = 0; t < 8; t++) {
            const int idx = t * 512 + tid;          // 12 bits
            const int rlo = idx & 15;
            const int bid = (idx >> 4) & 63;
            const int r = ((idx >> 10) << 4) | rlo;
            const int j = bid & (hf - 1);
            const int k = ((bid >> s) << (s + 1)) + j;
            w8[t] = twg[j << (6 - s)];
            i0[t] = IDX(r, k);
            i1[t] = IDX(r, k + hf);
            xl[t] = D[i0[t]];
            xh[t] = D[i1[t]];
        }
#pragma unroll
        for (int t = 0; t < 8; t++) {
            const float wy = inv ? -w8[t].y : w8[t].y;
            const float tr = w8[t].x * xh[t].x - wy * xh[t].y;
            const float ti = w8[t].x * xh[t].y + wy * xh[t].x;
            D[i0[t]] = make_float2(xl[t].x + tr, xl[t].y + ti);
            D[i1[t]] = make_float2(xl[t].x - tr, xl[t].y - ti);
        }
        __syncthreads();
    }
}

// ======================= Fused forward 2D rFFT ==============================
__global__ __launch_bounds__(512, 4) void k_fwd2d(const float* __restrict__ x,
                                                  float2* __restrict__ s0,
                                                  const float2* __restrict__ twg) {
    __shared__ float2 D[8192];           // exactly 64 KB
    const int tid = threadIdx.x;
    const int bc = blockIdx.x;

    // load + pack h-row pairs: Z[hp][w] = x[2hp][w] + i x[2hp+1][w], bitrev w.
    const float* xr = x + (size_t)bc * (NH * NW);
#pragma unroll
    for (int t = 0; t < 4; t++) {
        int i = t * 512 + tid;           // 2048 tasks x 4 elements
        int hp = i >> 5;
        int w0 = (i & 31) * 4;
        float4 a = *(const float4*)(xr + (size_t)(2 * hp) * NW + w0);
        float4 b = *(const float4*)(xr + (size_t)(2 * hp + 1) * NW + w0);
        D[IDX(hp, bitrev7(w0 + 0))] = make_float2(a.x, b.x);
        D[IDX(hp, bitrev7(w0 + 1))] = make_float2(a.y, b.y);
        D[IDX(hp, bitrev7(w0 + 2))] = make_float2(a.z, b.z);
        D[IDX(hp, bitrev7(w0 + 3))] = make_float2(a.w, b.w);
    }
    __syncthreads();
    fft64x128(D, twg, tid, false);       // row FFTs (over w)

    // unpack rfft pairs + transpose to [u][h] (h at bitrev positions).
    // task (hp, j): j=0 handles u=0 & u=64 (real), j=1..63 handles u=j.
    float2 ra[8], rb[8];
#pragma unroll
    for (int t = 0; t < 8; t++) {
        int i = t * 512 + tid;
        int hp = i >> 6, j = i & 63;
        ra[t] = D[IDX(hp, j)];
        rb[t] = D[IDX(hp, j ? (128 - j) : 64)];
    }
    __syncthreads();
#pragma unroll
    for (int t = 0; t < 8; t++) {
        int i = t * 512 + tid;
        int hp = i >> 6, j = i & 63;
        int c0 = bitrev7(2 * hp), c1 = bitrev7(2 * hp + 1);
        float2 a = ra[t], b = rb[t];
        if (j == 0) {                    // rows 0/64 are real: pack as one col
            D[IDX(0, c0)] = make_float2(a.x, b.x);
            D[IDX(0, c1)] = make_float2(a.y, b.y);
        } else {
            // Xe = (a+conj b)/2 -> row 2hp; Xo = (a-conj b)/(2i) -> row 2hp+1
            D[IDX(j, c0)] = make_float2(0.5f * (a.x + b.x), 0.5f * (a.y - b.y));
            D[IDX(j, c1)] = make_float2(0.5f * (a.y + b.y), 0.5f * (b.x - a.x));
        }
    }
    __syncthreads();
    fft64x128(D, twg, tid, false);       // column FFTs (over h)

    // write spectrum: v=1..63 direct; v=0 & v=64 unpacked from packed row 0.
    float2* o = s0 + (size_t)bc * NM;
#pragma unroll
    for (int t = 0; t < 16; t++) {
        int i = t * 512 + tid;           // 8192 tasks x 1 element
        int r = i >> 7, k = i & 127;
        if (r) {
            float2 v = D[IDX(r, k)];
            o[r * 128 + k] = make_float2(v.x * INV_N, v.y * INV_N);
        } else {
            float2 ck = D[IDX(0, k)];
            float2 cm = D[IDX(0, (128 - k) & 127)];
            o[k] = make_float2(0.5f * (ck.x + cm.x) * INV_N,
                               0.5f * (ck.y - cm.y) * INV_N);
            o[64 * 128 + k] = make_float2(0.5f * (ck.y + cm.y) * INV_N,
                                          0.5f * (cm.x - ck.x) * INV_N);
        }
    }
}

// ======================= Fused inverse 2D rFFT ==============================
__global__ __launch_bounds__(512, 4) void k_inv2d(const float2* __restrict__ y,
                                                  float* __restrict__ out,
                                                  const float2* __restrict__ twg) {
    __shared__ float2 D[8192];
    const int tid = threadIdx.x;
    const int bc = blockIdx.x;

    // load spectrum (4 consecutive k per thread: coalesced 32B global reads,
    // bitrev LDS writes spread banks via kq bits). v=0/64 Hermitian-
    // symmetrized (== reference's .real drop) and packed into row 0.
    const float2* Yb = y + (size_t)bc * NM;
#pragma unroll
    for (int t = 0; t < 4; t++) {
        int i = t * 512 + tid;           // 2048 tasks x 4 elements
        int r = i >> 5;
        int kq = (i & 31) * 4;
        if (r) {
            const float2* p = Yb + r * 128 + kq;
            float4 v01 = *(const float4*)(p);
            float4 v23 = *(const float4*)(p + 2);
            D[IDX(r, bitrev7(kq + 0))] = make_float2(v01.x, v01.y);
            D[IDX(r, bitrev7(kq + 1))] = make_float2(v01.z, v01.w);
            D[IDX(r, bitrev7(kq + 2))] = make_float2(v23.x, v23.y);
            D[IDX(r, bitrev7(kq + 3))] = make_float2(v23.z, v23.w);
        } else {
#pragma unroll
            for (int dw = 0; dw < 4; dw++) {
                int k = kq + dw;
                int m = (128 - k) & 127;
                float2 a = Yb[k],            am = Yb[m];
                float2 b = Yb[64 * 128 + k], bm = Yb[64 * 128 + m];
                float h0x = 0.5f * (a.x + am.x), h0y = 0.5f * (a.y - am.y);
                float h6x = 0.5f * (b.x + bm.x), h6y = 0.5f * (b.y - bm.y);
                D[IDX(0, bitrev7(k))] = make_float2(h0x - h6y, h0y + h6x);
            }
        }
    }
    __syncthreads();
    fft64x128(D, twg, tid, true);        // column iFFTs (k -> h)

    // transpose + Hermitian-extend to Z[hp][u] (u at bitrev positions).
    // remap: hp&15 <- lane&15, j low 2 bits <- lane bits 4..5 so both the
    // column-pair reads and the bitrev-row writes stay <=4 lanes/bank-pair.
    float2 ra[8], rb[8];
#pragma unroll
    for (int t = 0; t < 8; t++) {
        int i = t * 512 + tid;           // 12 bits
        int hp = (i & 15) | (((i >> 10) & 3) << 4);
        int j  = ((i >> 4) & 3) | (((i >> 6) & 15) << 2);
        ra[t] = D[IDX(j, 2 * hp)];
        rb[t] = D[IDX(j, 2 * hp + 1)];
    }
    __syncthreads();
#pragma unroll
    for (int t = 0; t < 8; t++) {
        int i = t * 512 + tid;
        int hp = (i & 15) | (((i >> 10) & 3) << 4);
        int j  = ((i >> 4) & 3) | (((i >> 6) & 15) << 2);
        float2 e = ra[t], f = rb[t];
        if (j == 0) {                    // row 0 held (ReX_h[0], ReX_h[64])
            D[IDX(hp, bitrev7(0))]  = make_float2(e.x, f.x);
            D[IDX(hp, bitrev7(64))] = make_float2(e.y, f.y);
        } else {
            // Z[hp][j] = e + i f ;  Z[hp][128-j] = conj(e) + i conj(f)
            D[IDX(hp, bitrev7(j))]       = make_float2(e.x - f.y, e.y + f.x);
            D[IDX(hp, bitrev7(128 - j))] = make_float2(e.x + f.y, f.x - e.y);
        }
    }
    __syncthreads();
    fft64x128(D, twg, tid, true);        // row iFFTs (u -> w)

    // output: z[hp][w] = x[2hp][w] + i x[2hp+1][w]. One float2 per thread at
    // natural (hp, w=lane): LDS spread by w, global stores coalesced scalars.
    float* ob = out + (size_t)bc * (NH * NW);
#pragma unroll
    for (int t = 0; t < 16; t++) {
        int i = t * 512 + tid;           // 8192 tasks x 1 element
        int hp = i >> 7, w = i & 127;
        float2 v = D[IDX(hp, w)];
        ob[(size_t)(2 * hp) * NW + w]     = v.x * INV_N;
        ob[(size_t)(2 * hp + 1) * NW + w] = v.y * INV_N;
    }
}

// ======================= Weight prep + twiddle table ========================
__global__ __launch_bounds__(256) void k_prep_w(const float* __restrict__ w1,
                                                const float* __restrict__ w2,
                                                ushortT* __restrict__ Wp,
                                                float2* __restrict__ twg) {
    if (blockIdx.x == 0 && threadIdx.x < 64) {
        float s, c;
        sincosf(-3.14159265358979323846f * (float)threadIdx.x / 64.0f, &s, &c);
        twg[threadIdx.x] = make_float2(c, s);
    }
    int idx = blockIdx.x * 256 + threadIdx.x;      // 2*4*256*256
    int k = idx & 255;
    int n = (idx >> 8) & 255;
    int g = (idx >> 16) & 3;
    int l = idx >> 18;
    const float* w = l ? w2 : w1;
    int kk = l ? sigma(k) : k;
    int ki = kk & 127, no = n & 127;
    float val;
    if (kk < 128) {
        val = (n < 128) ? w[((0 * NG + g) * ND + ki) * ND + no]
                        : w[((1 * NG + g) * ND + ki) * ND + no];
    } else {
        val = (n < 128) ? -w[((1 * NG + g) * ND + ki) * ND + no]
                        :  w[((0 * NG + g) * ND + ki) * ND + no];
    }
    Wp[((size_t)(l * NG + g) * 256 + n) * 256 + k] = f2b(val);
}

// ======================= Fused GEMM1 + GEMM2 (unchanged) ====================
__global__ __launch_bounds__(512, 4) void k_gemm_fused(float2* __restrict__ S,
                                                       const ushortT* __restrict__ Wp,
                                                       const float* __restrict__ B1,
                                                       const float* __restrict__ B2) {
    __shared__ unsigned char smem[65536];
    ushortT* Alds = (ushortT*)smem;
    ushortT* o1l  = (ushortT*)smem;
    float2*  E    = (float2*)smem;

    const int tid = threadIdx.x;
    const int mt = blockIdx.x, bk = blockIdx.y;
    const int g = bk & 3;
    const int m0 = mt * 128;
    const int lane = tid & 63, wid = tid >> 6;
    const int col = lane & 15, quad = lane >> 4;
    const int wm = wid & 1, wn = wid >> 1;          // wn in [0,4)

    float2* Ab = S + (size_t)(bk * ND) * NM + m0;
    const ushortT* Wg1 = Wp + (size_t)g * 65536;
    const ushortT* Wg2 = Wp + (size_t)(NG + g) * 65536;

    f32x4 acc[4][4];
#pragma unroll
    for (int i = 0; i < 4; i++)
#pragma unroll
        for (int j = 0; j < 4; j++) acc[i][j] = f32x4{0.f, 0.f, 0.f, 0.f};

    // ---- phase 1: gemm1. A staged fp32->bf16; W1 fragments straight from L2.
    for (int s = 0; s < 2; s++) {
        const int cs = s * 64;
        __syncthreads();
        {
            const int oct = tid >> 6;               // 0..7
            const int mp = (tid & 63) * 2;          // 0..126
            union { ushortT u[8]; uint4 v; } re0, re1, im0, im1;
#pragma unroll
            for (int j = 0; j < 8; j++) {
                const float4 v = *(const float4*)(Ab + (size_t)(cs + oct * 8 + j) * NM + mp);
                re0.u[j] = f2b(v.x); im0.u[j] = f2b(v.y);
                re1.u[j] = f2b(v.z); im1.u[j] = f2b(v.w);
            }
            *(uint4*)&Alds[(oct * 128 + mp) * 8] = re0.v;
            *(uint4*)&Alds[(oct * 128 + mp + 1) * 8] = re1.v;
            *(uint4*)&Alds[((8 + oct) * 128 + mp) * 8] = im0.v;
            *(uint4*)&Alds[((8 + oct) * 128 + mp + 1) * 8] = im1.v;
        }
        __syncthreads();
#pragma unroll
        for (int h = 0; h < 2; h++) {
            const int kbase = h * 128 + cs;
#pragma unroll
            for (int ksl = 0; ksl < 2; ksl++) {
                bf16x8 a[4];
#pragma unroll
                for (int mi = 0; mi < 4; mi++)
                    a[mi] = *(const bf16x8*)&Alds[((h * 8 + ksl * 4 + quad) * 128
                                                   + wm * 64 + mi * 16 + col) * 8];
#pragma unroll
                for (int ni = 0; ni < 4; ni++) {
                    const int n = wn * 64 + ni * 16 + col;
                    bf16x8 b = *(const bf16x8*)(Wg1 + (size_t)n * 256 + kbase
                                                + (ksl * 4 + quad) * 8);
#pragma unroll
                    for (int mi = 0; mi < 4; mi++)
                        acc[mi][ni] = __builtin_amdgcn_mfma_f32_16x16x32_bf16(
                            a[mi], b, acc[mi][ni], 0, 0, 0);
                }
            }
        }
    }

    // ---- phase 2: bias + relu -> bf16 o1 tile in LDS.
    float bR[4];
#pragma unroll
    for (int ni = 0; ni < 4; ni++) {
        const int n = wn * 64 + ni * 16 + col;
        bR[ni] = (n < 128) ? B1[g * ND + n] : B1[512 + g * ND + (n - 128)];
    }
    __syncthreads();                                // all Alds reads done
    {
        const int kq = col * 2 + (wn >> 1);
        const int xo = col & 7;                     // (kq>>1)&7
        const int pos = (wn & 1) * 4;
#pragma unroll
        for (int mi = 0; mi < 4; mi++)
#pragma unroll
            for (int r = 0; r < 4; r++) {
                const int ml = wm * 64 + mi * 16 + quad * 4 + r;
                union { ushortT u[4]; uint2 v; } pk;
#pragma unroll
                for (int ni = 0; ni < 4; ni++)
                    pk.u[ni] = f2b(fmaxf(acc[mi][ni][r] + bR[ni], 0.f));
                *(uint2*)&o1l[(kq * 128 + (ml ^ xo)) * 8 + pos] = pk.v;
            }
    }
    __syncthreads();

    // ---- phase 3: gemm2. A from o1 LDS; W2 fragments straight from L2.
#pragma unroll
    for (int i = 0; i < 4; i++)
#pragma unroll
        for (int j = 0; j < 4; j++) acc[i][j] = f32x4{0.f, 0.f, 0.f, 0.f};

#pragma unroll
    for (int kqs = 0; kqs < 8; kqs++) {
        const int kq = kqs * 4 + quad;
        const int xo = (kq >> 1) & 7;
        bf16x8 a[4];
#pragma unroll
        for (int mi = 0; mi < 4; mi++)
            a[mi] = *(const bf16x8*)&o1l[(kq * 128 + ((wm * 64 + mi * 16 + col) ^ xo)) * 8];
#pragma unroll
        for (int ni = 0; ni < 4; ni++) {
            const int n = wn * 64 + ni * 16 + col;
            bf16x8 b = *(const bf16x8*)(Wg2 + (size_t)n * 256 + (size_t)kq * 8);
#pragma unroll
            for (int mi = 0; mi < 4; mi++)
                acc[mi][ni] = __builtin_amdgcn_mfma_f32_16x16x32_bf16(
                    a[mi], b, acc[mi][ni], 0, 0, 0);
        }
    }

    // ---- epilogue: pair (real, imag) across waves via LDS, *origin, RMW.
    const int ri = wn >> 1;                          // 0 = real half, 1 = imag
#pragma unroll
    for (int p = 0; p < 4; p++) {
        __syncthreads();
        if ((wn & 1) == (p >> 1)) {
#pragma unroll
            for (int q2 = 0; q2 < 2; q2++) {
                const int nic = (p & 1) * 2 + q2;
                const int ch_l = q2 * 16 + col;
                const int ch = p * 32 + ch_l;
                const float bias = ri ? B2[512 + g * ND + ch] : B2[g * ND + ch];
#pragma unroll
                for (int mi = 0; mi < 4; mi++)
#pragma unroll
                    for (int r = 0; r < 4; r++) {
                        const int ml = wm * 64 + mi * 16 + quad * 4 + r;
                        ((float*)&E[ch_l * 129 + ml])[ri] = acc[mi][nic][r] + bias;
                    }
            }
        }
        __syncthreads();
#pragma unroll
        for (int j = 0; j < 8; j++) {
            const int idx = j * 512 + tid;
            const int ch_l = idx >> 7, ml = idx & 127;
            const float2 v = E[ch_l * 129 + ml];
            float2* Yp = Ab + (size_t)(p * 32 + ch_l) * NM + ml;
            const float2 o = *Yp;
            *Yp = make_float2(v.x * o.x - v.y * o.y, v.x * o.y + v.y * o.x);
        }
    }
}

// ======================= launch =============================================
extern "C" void kernel_launch(void* const* d_in, const int* in_sizes, int n_in,
                              void* d_out, int out_size, void* d_ws, size_t ws_size,
                              hipStream_t stream) {
    (void)in_sizes; (void)n_in; (void)out_size; (void)ws_size;
    const float* x  = (const float*)d_in[0];
    const float* w1 = (const float*)d_in[1];
    const float* w2 = (const float*)d_in[2];
    const float* b1 = (const float*)d_in[3];
    const float* b2 = (const float*)d_in[4];
    float* outp = (float*)d_out;

    float2* buf1 = (float2*)d_ws;                        // 272,629,760 B
    char*   ws2  = (char*)d_ws + (size_t)NB * NC * NM * sizeof(float2);
    ushortT* Wp  = (ushortT*)(ws2 + (size_t)144 * 1024 * 1024);   // 1 MB
    float2* twg  = (float2*)((char*)Wp + (size_t)1048576);        // 512 B

    k_prep_w<<<dim3(2048), 256, 0, stream>>>(w1, w2, Wp, twg);
    k_fwd2d<<<dim3(NB * NC), 512, 0, stream>>>(x, buf1, twg);
    k_gemm_fused<<<dim3(NM / 128, NB * NG), 512, 0, stream>>>(buf1, Wp, b1, b2);
    k_inv2d<<<dim3(NB * NC), 512, 0, stream>>>(buf1, outp, twg);
}

// Round 5
// 847.280 us; speedup vs baseline: 1.3237x; 1.3237x over previous
//
#include <hip/hip_runtime.h>
#include <hip/hip_bf16.h>

// AFNO spectral block. Round 7: radix-4 FFT passes + 1024-thread FFT blocks.
// Pipeline: prep_w -> fwd2d -> gemm_fused -> inv2d
//
// buf1: fp32 float2 spectrum [bc=4096][m=8320], m = v*128 + h  (272.6 MB)
// Wpack: bf16 [2 layers][4 groups][n=256][k=256]; twg (64 f2) after it.
//
// k_fwd2d / k_inv2d: one block per (b,c) image, 1024 threads, 64 KB LDS tile
//   [64 rows][128 cols] float2, XOR swizzle IDX(r,c)=r*128+(c^(r&15)).
//   FFT = 3 radix-4 passes (fusing radix-2 stage pairs 0/1, 2/3, 4/5) +
//   1 radix-2 pass (stage 6): half the LDS stage traffic, 4 syncs instead
//   of 7. 2 blocks/CU x 16 waves = 32 waves/CU target occupancy.
//   All LDS instructions spread <=4 lanes/bank-pair (lane bits 0..3 -> row,
//   bits 4..5 -> group/butterfly).

#define NB    8
#define NC    512
#define NG    4
#define ND    128
#define NH    128
#define NW    128
#define NWF   65
#define NM    (NWF * NH)        // 8320
#define INV_N 0.0078125f        // 1/128

typedef unsigned short ushortT;
typedef __bf16 bf16x8 __attribute__((ext_vector_type(8)));
typedef float f32x4 __attribute__((ext_vector_type(4)));

__device__ __forceinline__ ushortT f2b(float f) {
    __hip_bfloat16 h = __float2bfloat16(f);
    return __builtin_bit_cast(ushortT, h);
}

// involution permutation for o1's k ordering (store-side packs contiguous k')
__device__ __forceinline__ int sigma(int n) {
    return ((n & 15) << 4) | ((n >> 4) & 7) | ((n & 128) >> 4);
}

__device__ __forceinline__ int bitrev7(int x) {
    return (int)(__brev((unsigned)x) >> 25);
}

// LDS tile index: row r in [0,64), col c in [0,128).
__device__ __forceinline__ int IDX(int r, int c) {
    return (r << 7) + (c ^ (r & 15));
}

__device__ __forceinline__ float2 cmul(float2 a, float2 b) {
    return make_float2(a.x * b.x - a.y * b.y, a.x * b.y + a.y * b.x);
}

// Radix-4 pass fusing radix-2 DIT stages s and s+1 (h = 1<<s).
// 64 rows x 32 groups = 2048 tasks; 1024 threads, 2 tasks/thread, each task
// owns its 4 elements (no cross-thread hazard within the pass).
template <bool INV>
__device__ __forceinline__ void r4pass(float2* D, const float2* __restrict__ twg,
                                       int tid, int s) {
    const int h = 1 << s;
#pragma unroll
    for (int t = 0; t < 2; t++) {
        const int idx = t * 1024 + tid;        // 11 bits
        const int rlo = idx & 15;
        const int gid = (idx >> 4) & 31;
        const int r = ((idx >> 9) << 4) | rlo;
        const int j = gid & (h - 1);
        const int base = ((gid >> s) << (s + 2)) + j;
        float2 t2 = twg[j << (5 - s)];         // stage s+1 twiddle
        float2 t1 = twg[j << (6 - s)];         // stage s twiddle (= t2^2)
        if (INV) { t1.y = -t1.y; t2.y = -t2.y; }
        float2 a = D[IDX(r, base)];
        float2 b = D[IDX(r, base + h)];
        float2 c = D[IDX(r, base + 2 * h)];
        float2 d = D[IDX(r, base + 3 * h)];
        float2 tb = cmul(t1, b), td = cmul(t1, d);
        float2 a1 = make_float2(a.x + tb.x, a.y + tb.y);
        float2 b1 = make_float2(a.x - tb.x, a.y - tb.y);
        float2 c1 = make_float2(c.x + td.x, c.y + td.y);
        float2 d1 = make_float2(c.x - td.x, c.y - td.y);
        float2 tc = cmul(t2, c1), ud = cmul(t2, d1);
        // odd-pair stage-(s+1) twiddle is t2 * (-i) fwd / t2 * (+i) inv
        float2 rot = INV ? make_float2(-ud.y, ud.x) : make_float2(ud.y, -ud.x);
        D[IDX(r, base)]         = make_float2(a1.x + tc.x, a1.y + tc.y);
        D[IDX(r, base + h)]     = make_float2(b1.x + rot.x, b1.y + rot.y);
        D[IDX(r, base + 2 * h)] = make_float2(a1.x - tc.x, a1.y - tc.y);
        D[IDX(r, base + 3 * h)] = make_float2(b1.x - rot.x, b1.y - rot.y);
    }
    __syncthreads();
}

// Final radix-2 stage s=6: pairs (j, j+64), twiddle twg[j].
template <bool INV>
__device__ __forceinline__ void r2final(float2* D, const float2* __restrict__ twg,
                                        int tid) {
#pragma unroll
    for (int t = 0; t < 4; t++) {
        const int idx = t * 1024 + tid;        // 12 bits
        const int rlo = idx & 15;
        const int j = (idx >> 4) & 63;
        const int r = ((idx >> 10) << 4) | rlo;
        float2 w = twg[j];
        if (INV) w.y = -w.y;
        float2 xl = D[IDX(r, j)];
        float2 xh = D[IDX(r, j + 64)];
        const float tr = w.x * xh.x - w.y * xh.y;
        const float ti = w.x * xh.y + w.y * xh.x;
        D[IDX(r, j)]      = make_float2(xl.x + tr, xl.y + ti);
        D[IDX(r, j + 64)] = make_float2(xl.x - tr, xl.y - ti);
    }
    __syncthreads();
}

template <bool INV>
__device__ __forceinline__ void fft64x128(float2* D, const float2* __restrict__ twg,
                                          int tid) {
    r4pass<INV>(D, twg, tid, 0);
    r4pass<INV>(D, twg, tid, 2);
    r4pass<INV>(D, twg, tid, 4);
    r2final<INV>(D, twg, tid);
}

// ======================= Fused forward 2D rFFT ==============================
__global__ __launch_bounds__(1024, 8) void k_fwd2d(const float* __restrict__ x,
                                                   float2* __restrict__ s0,
                                                   const float2* __restrict__ twg) {
    __shared__ float2 D[8192];           // exactly 64 KB
    const int tid = threadIdx.x;
    const int bc = blockIdx.x;

    // load + pack h-row pairs: Z[hp][w] = x[2hp][w] + i x[2hp+1][w], bitrev w.
    const float* xr = x + (size_t)bc * (NH * NW);
#pragma unroll
    for (int t = 0; t < 2; t++) {
        int i = t * 1024 + tid;          // 2048 tasks x 4 elements
        int hp = i >> 5;
        int w0 = (i & 31) * 4;
        float4 a = *(const float4*)(xr + (size_t)(2 * hp) * NW + w0);
        float4 b = *(const float4*)(xr + (size_t)(2 * hp + 1) * NW + w0);
        D[IDX(hp, bitrev7(w0 + 0))] = make_float2(a.x, b.x);
        D[IDX(hp, bitrev7(w0 + 1))] = make_float2(a.y, b.y);
        D[IDX(hp, bitrev7(w0 + 2))] = make_float2(a.z, b.z);
        D[IDX(hp, bitrev7(w0 + 3))] = make_float2(a.w, b.w);
    }
    __syncthreads();
    fft64x128<false>(D, twg, tid);       // row FFTs (over w)

    // unpack rfft pairs + transpose to [u][h] (h at bitrev positions).
    // task (hp, j): j=0 handles u=0 & u=64 (real), j=1..63 handles u=j.
    float2 ra[4], rb[4];
#pragma unroll
    for (int t = 0; t < 4; t++) {
        int i = t * 1024 + tid;          // 4096 tasks
        int hp = i >> 6, j = i & 63;
        ra[t] = D[IDX(hp, j)];
        rb[t] = D[IDX(hp, j ? (128 - j) : 64)];
    }
    __syncthreads();
#pragma unroll
    for (int t = 0; t < 4; t++) {
        int i = t * 1024 + tid;
        int hp = i >> 6, j = i & 63;
        int c0 = bitrev7(2 * hp), c1 = bitrev7(2 * hp + 1);
        float2 a = ra[t], b = rb[t];
        if (j == 0) {                    // rows 0/64 are real: pack as one col
            D[IDX(0, c0)] = make_float2(a.x, b.x);
            D[IDX(0, c1)] = make_float2(a.y, b.y);
        } else {
            // Xe = (a+conj b)/2 -> row 2hp; Xo = (a-conj b)/(2i) -> row 2hp+1
            D[IDX(j, c0)] = make_float2(0.5f * (a.x + b.x), 0.5f * (a.y - b.y));
            D[IDX(j, c1)] = make_float2(0.5f * (a.y + b.y), 0.5f * (b.x - a.x));
        }
    }
    __syncthreads();
    fft64x128<false>(D, twg, tid);       // column FFTs (over h)

    // write spectrum: v=1..63 direct; v=0 & v=64 unpacked from packed row 0.
    float2* o = s0 + (size_t)bc * NM;
#pragma unroll
    for (int t = 0; t < 8; t++) {
        int i = t * 1024 + tid;          // 8192 tasks x 1 element
        int r = i >> 7, k = i & 127;
        if (r) {
            float2 v = D[IDX(r, k)];
            o[r * 128 + k] = make_float2(v.x * INV_N, v.y * INV_N);
        } else {
            float2 ck = D[IDX(0, k)];
            float2 cm = D[IDX(0, (128 - k) & 127)];
            o[k] = make_float2(0.5f * (ck.x + cm.x) * INV_N,
                               0.5f * (ck.y - cm.y) * INV_N);
            o[64 * 128 + k] = make_float2(0.5f * (ck.y + cm.y) * INV_N,
                                          0.5f * (cm.x - ck.x) * INV_N);
        }
    }
}

// ======================= Fused inverse 2D rFFT ==============================
__global__ __launch_bounds__(1024, 8) void k_inv2d(const float2* __restrict__ y,
                                                   float* __restrict__ out,
                                                   const float2* __restrict__ twg) {
    __shared__ float2 D[8192];
    const int tid = threadIdx.x;
    const int bc = blockIdx.x;

    // load spectrum (4 consecutive k per thread: coalesced 32B global reads).
    // v=0/64 Hermitian-symmetrized (== reference's .real drop), packed row 0.
    const float2* Yb = y + (size_t)bc * NM;
#pragma unroll
    for (int t = 0; t < 2; t++) {
        int i = t * 1024 + tid;          // 2048 tasks x 4 elements
        int r = i >> 5;
        int kq = (i & 31) * 4;
        if (r) {
            const float2* p = Yb + r * 128 + kq;
            float4 v01 = *(const float4*)(p);
            float4 v23 = *(const float4*)(p + 2);
            D[IDX(r, bitrev7(kq + 0))] = make_float2(v01.x, v01.y);
            D[IDX(r, bitrev7(kq + 1))] = make_float2(v01.z, v01.w);
            D[IDX(r, bitrev7(kq + 2))] = make_float2(v23.x, v23.y);
            D[IDX(r, bitrev7(kq + 3))] = make_float2(v23.z, v23.w);
        } else {
#pragma unroll
            for (int dw = 0; dw < 4; dw++) {
                int k = kq + dw;
                int m = (128 - k) & 127;
                float2 a = Yb[k],            am = Yb[m];
                float2 b = Yb[64 * 128 + k], bm = Yb[64 * 128 + m];
                float h0x = 0.5f * (a.x + am.x), h0y = 0.5f * (a.y - am.y);
                float h6x = 0.5f * (b.x + bm.x), h6y = 0.5f * (b.y - bm.y);
                D[IDX(0, bitrev7(k))] = make_float2(h0x - h6y, h0y + h6x);
            }
        }
    }
    __syncthreads();
    fft64x128<true>(D, twg, tid);        // column iFFTs (k -> h)

    // transpose + Hermitian-extend to Z[hp][u] (u at bitrev positions).
    // hp&15 <- lane&15, j low 2 bits <- lane bits 4..5 (bank spread both ways)
    float2 ra[4], rb[4];
#pragma unroll
    for (int t = 0; t < 4; t++) {
        int i = t * 1024 + tid;          // 12 bits
        int hp = (i & 15) | (((i >> 10) & 3) << 4);
        int j  = ((i >> 4) & 3) | (((i >> 6) & 15) << 2);
        ra[t] = D[IDX(j, 2 * hp)];
        rb[t] = D[IDX(j, 2 * hp + 1)];
    }
    __syncthreads();
#pragma unroll
    for (int t = 0; t < 4; t++) {
        int i = t * 1024 + tid;
        int hp = (i & 15) | (((i >> 10) & 3) << 4);
        int j  = ((i >> 4) & 3) | (((i >> 6) & 15) << 2);
        float2 e = ra[t], f = rb[t];
        if (j == 0) {                    // row 0 held (ReX_h[0], ReX_h[64])
            D[IDX(hp, bitrev7(0))]  = make_float2(e.x, f.x);
            D[IDX(hp, bitrev7(64))] = make_float2(e.y, f.y);
        } else {
            // Z[hp][j] = e + i f ;  Z[hp][128-j] = conj(e) + i conj(f)
            D[IDX(hp, bitrev7(j))]       = make_float2(e.x - f.y, e.y + f.x);
            D[IDX(hp, bitrev7(128 - j))] = make_float2(e.x + f.y, f.x - e.y);
        }
    }
    __syncthreads();
    fft64x128<true>(D, twg, tid);        // row iFFTs (u -> w)

    // output: z[hp][w] = x[2hp][w] + i x[2hp+1][w]. One float2 per thread at
    // natural (hp, w): LDS spread by w, global stores coalesced scalars.
    float* ob = out + (size_t)bc * (NH * NW);
#pragma unroll
    for (int t = 0; t < 8; t++) {
        int i = t * 1024 + tid;          // 8192 tasks x 1 element
        int hp = i >> 7, w = i & 127;
        float2 v = D[IDX(hp, w)];
        ob[(size_t)(2 * hp) * NW + w]     = v.x * INV_N;
        ob[(size_t)(2 * hp + 1) * NW + w] = v.y * INV_N;
    }
}

// ======================= Weight prep + twiddle table ========================
__global__ __launch_bounds__(256) void k_prep_w(const float* __restrict__ w1,
                                                const float* __restrict__ w2,
                                                ushortT* __restrict__ Wp,
                                                float2* __restrict__ twg) {
    if (blockIdx.x == 0 && threadIdx.x < 64) {
        float s, c;
        sincosf(-3.14159265358979323846f * (float)threadIdx.x / 64.0f, &s, &c);
        twg[threadIdx.x] = make_float2(c, s);
    }
    int idx = blockIdx.x * 256 + threadIdx.x;      // 2*4*256*256
    int k = idx & 255;
    int n = (idx >> 8) & 255;
    int g = (idx >> 16) & 3;
    int l = idx >> 18;
    const float* w = l ? w2 : w1;
    int kk = l ? sigma(k) : k;
    int ki = kk & 127, no = n & 127;
    float val;
    if (kk < 128) {
        val = (n < 128) ? w[((0 * NG + g) * ND + ki) * ND + no]
                        : w[((1 * NG + g) * ND + ki) * ND + no];
    } else {
        val = (n < 128) ? -w[((1 * NG + g) * ND + ki) * ND + no]
                        :  w[((0 * NG + g) * ND + ki) * ND + no];
    }
    Wp[((size_t)(l * NG + g) * 256 + n) * 256 + k] = f2b(val);
}

// ======================= Fused GEMM1 + GEMM2 (unchanged) ====================
__global__ __launch_bounds__(512, 4) void k_gemm_fused(float2* __restrict__ S,
                                                       const ushortT* __restrict__ Wp,
                                                       const float* __restrict__ B1,
                                                       const float* __restrict__ B2) {
    __shared__ unsigned char smem[65536];
    ushortT* Alds = (ushortT*)smem;
    ushortT* o1l  = (ushortT*)smem;
    float2*  E    = (float2*)smem;

    const int tid = threadIdx.x;
    const int mt = blockIdx.x, bk = blockIdx.y;
    const int g = bk & 3;
    const int m0 = mt * 128;
    const int lane = tid & 63, wid = tid >> 6;
    const int col = lane & 15, quad = lane >> 4;
    const int wm = wid & 1, wn = wid >> 1;          // wn in [0,4)

    float2* Ab = S + (size_t)(bk * ND) * NM + m0;
    const ushortT* Wg1 = Wp + (size_t)g * 65536;
    const ushortT* Wg2 = Wp + (size_t)(NG + g) * 65536;

    f32x4 acc[4][4];
#pragma unroll
    for (int i = 0; i < 4; i++)
#pragma unroll
        for (int j = 0; j < 4; j++) acc[i][j] = f32x4{0.f, 0.f, 0.f, 0.f};

    // ---- phase 1: gemm1. A staged fp32->bf16; W1 fragments straight from L2.
    for (int s = 0; s < 2; s++) {
        const int cs = s * 64;
        __syncthreads();
        {
            const int oct = tid >> 6;               // 0..7
            const int mp = (tid & 63) * 2;          // 0..126
            union { ushortT u[8]; uint4 v; } re0, re1, im0, im1;
#pragma unroll
            for (int j = 0; j < 8; j++) {
                const float4 v = *(const float4*)(Ab + (size_t)(cs + oct * 8 + j) * NM + mp);
                re0.u[j] = f2b(v.x); im0.u[j] = f2b(v.y);
                re1.u[j] = f2b(v.z); im1.u[j] = f2b(v.w);
            }
            *(uint4*)&Alds[(oct * 128 + mp) * 8] = re0.v;
            *(uint4*)&Alds[(oct * 128 + mp + 1) * 8] = re1.v;
            *(uint4*)&Alds[((8 + oct) * 128 + mp) * 8] = im0.v;
            *(uint4*)&Alds[((8 + oct) * 128 + mp + 1) * 8] = im1.v;
        }
        __syncthreads();
#pragma unroll
        for (int h = 0; h < 2; h++) {
            const int kbase = h * 128 + cs;
#pragma unroll
            for (int ksl = 0; ksl < 2; ksl++) {
                bf16x8 a[4];
#pragma unroll
                for (int mi = 0; mi < 4; mi++)
                    a[mi] = *(const bf16x8*)&Alds[((h * 8 + ksl * 4 + quad) * 128
                                                   + wm * 64 + mi * 16 + col) * 8];
#pragma unroll
                for (int ni = 0; ni < 4; ni++) {
                    const int n = wn * 64 + ni * 16 + col;
                    bf16x8 b = *(const bf16x8*)(Wg1 + (size_t)n * 256 + kbase
                                                + (ksl * 4 + quad) * 8);
#pragma unroll
                    for (int mi = 0; mi < 4; mi++)
                        acc[mi][ni] = __builtin_amdgcn_mfma_f32_16x16x32_bf16(
                            a[mi], b, acc[mi][ni], 0, 0, 0);
                }
            }
        }
    }

    // ---- phase 2: bias + relu -> bf16 o1 tile in LDS.
    float bR[4];
#pragma unroll
    for (int ni = 0; ni < 4; ni++) {
        const int n = wn * 64 + ni * 16 + col;
        bR[ni] = (n < 128) ? B1[g * ND + n] : B1[512 + g * ND + (n - 128)];
    }
    __syncthreads();                                // all Alds reads done
    {
        const int kq = col * 2 + (wn >> 1);
        const int xo = col & 7;                     // (kq>>1)&7
        const int pos = (wn & 1) * 4;
#pragma unroll
        for (int mi = 0; mi < 4; mi++)
#pragma unroll
            for (int r = 0; r < 4; r++) {
                const int ml = wm * 64 + mi * 16 + quad * 4 + r;
                union { ushortT u[4]; uint2 v; } pk;
#pragma unroll
                for (int ni = 0; ni < 4; ni++)
                    pk.u[ni] = f2b(fmaxf(acc[mi][ni][r] + bR[ni], 0.f));
                *(uint2*)&o1l[(kq * 128 + (ml ^ xo)) * 8 + pos] = pk.v;
            }
    }
    __syncthreads();

    // ---- phase 3: gemm2. A from o1 LDS; W2 fragments straight from L2.
#pragma unroll
    for (int i = 0; i < 4; i++)
#pragma unroll
        for (int j = 0; j < 4; j++) acc[i][j] = f32x4{0.f, 0.f, 0.f, 0.f};

#pragma unroll
    for (int kqs = 0; kqs < 8; kqs++) {
        const int kq = kqs * 4 + quad;
        const int xo = (kq >> 1) & 7;
        bf16x8 a[4];
#pragma unroll
        for (int mi = 0; mi < 4; mi++)
            a[mi] = *(const bf16x8*)&o1l[(kq * 128 + ((wm * 64 + mi * 16 + col) ^ xo)) * 8];
#pragma unroll
        for (int ni = 0; ni < 4; ni++) {
            const int n = wn * 64 + ni * 16 + col;
            bf16x8 b = *(const bf16x8*)(Wg2 + (size_t)n * 256 + (size_t)kq * 8);
#pragma unroll
            for (int mi = 0; mi < 4; mi++)
                acc[mi][ni] = __builtin_amdgcn_mfma_f32_16x16x32_bf16(
                    a[mi], b, acc[mi][ni], 0, 0, 0);
        }
    }

    // ---- epilogue: pair (real, imag) across waves via LDS, *origin, RMW.
    const int ri = wn >> 1;                          // 0 = real half, 1 = imag
#pragma unroll
    for (int p = 0; p < 4; p++) {
        __syncthreads();
        if ((wn & 1) == (p >> 1)) {
#pragma unroll
            for (int q2 = 0; q2 < 2; q2++) {
                const int nic = (p & 1) * 2 + q2;
                const int ch_l = q2 * 16 + col;
                const int ch = p * 32 + ch_l;
                const float bias = ri ? B2[512 + g * ND + ch] : B2[g * ND + ch];
#pragma unroll
                for (int mi = 0; mi < 4; mi++)
#pragma unroll
                    for (int r = 0; r < 4; r++) {
                        const int ml = wm * 64 + mi * 16 + quad * 4 + r;
                        ((float*)&E[ch_l * 129 + ml])[ri] = acc[mi][nic][r] + bias;
                    }
            }
        }
        __syncthreads();
#pragma unroll
        for (int j = 0; j < 8; j++) {
            const int idx = j * 512 + tid;
            const int ch_l = idx >> 7, ml = idx & 127;
            const float2 v = E[ch_l * 129 + ml];
            float2* Yp = Ab + (size_t)(p * 32 + ch_l) * NM + ml;
            const float2 o = *Yp;
            *Yp = make_float2(v.x * o.x - v.y * o.y, v.x * o.y + v.y * o.x);
        }
    }
}

// ======================= launch =============================================
extern "C" void kernel_launch(void* const* d_in, const int* in_sizes, int n_in,
                              void* d_out, int out_size, void* d_ws, size_t ws_size,
                              hipStream_t stream) {
    (void)in_sizes; (void)n_in; (void)out_size; (void)ws_size;
    const float* x  = (const float*)d_in[0];
    const float* w1 = (const float*)d_in[1];
    const float* w2 = (const float*)d_in[2];
    const float* b1 = (const float*)d_in[3];
    const float* b2 = (const float*)d_in[4];
    float* outp = (float*)d_out;

    float2* buf1 = (float2*)d_ws;                        // 272,629,760 B
    char*   ws2  = (char*)d_ws + (size_t)NB * NC * NM * sizeof(float2);
    ushortT* Wp  = (ushortT*)(ws2 + (size_t)144 * 1024 * 1024);   // 1 MB
    float2* twg  = (float2*)((char*)Wp + (size_t)1048576);        // 512 B

    k_prep_w<<<dim3(2048), 256, 0, stream>>>(w1, w2, Wp, twg);
    k_fwd2d<<<dim3(NB * NC), 1024, 0, stream>>>(x, buf1, twg);
    k_gemm_fused<<<dim3(NM / 128, NB * NG), 512, 0, stream>>>(buf1, Wp, b1, b2);
    k_inv2d<<<dim3(NB * NC), 1024, 0, stream>>>(buf1, outp, twg);
}

// Round 6
// 771.964 us; speedup vs baseline: 1.4528x; 1.0976x over previous
//
#include <hip/hip_runtime.h>
#include <hip/hip_bf16.h>

// AFNO spectral block. Round 8: bf16-packed spectrum interchange buffer.
// Pipeline: prep_w -> fwd2d -> gemm_fused -> inv2d
//
// buf1: packed bf16 spectrum [bc=4096][m=8320], uint = re|im<<16  (136.3 MB)
// Wpack: bf16 [2 layers][4 groups][n=256][k=256]; twg (64 f2) after it.
//
// The GEMM already rounded the spectrum to bf16 at staging; moving that
// rounding into fwd2d's store is round-once-either-way. New quantization:
// origin operand + final product (each <=0.2% rel) -- absmax headroom 3.6x.
//
// k_fwd2d / k_inv2d: one block per (b,c) image, 1024 threads, 64 KB LDS tile
//   [64 rows][128 cols] float2, XOR swizzle IDX(r,c)=r*128+(c^(r&15)).
//   FFT = 3 radix-4 passes + 1 radix-2 pass, fp32 internally.

#define NB    8
#define NC    512
#define NG    4
#define ND    128
#define NH    128
#define NW    128
#define NWF   65
#define NM    (NWF * NH)        // 8320
#define INV_N 0.0078125f        // 1/128

typedef unsigned short ushortT;
typedef unsigned int uintT;
typedef __bf16 bf16x8 __attribute__((ext_vector_type(8)));
typedef float f32x4 __attribute__((ext_vector_type(4)));

__device__ __forceinline__ ushortT f2b(float f) {
    __hip_bfloat16 h = __float2bfloat16(f);
    return __builtin_bit_cast(ushortT, h);
}

__device__ __forceinline__ uintT pk2(float a, float b) {
    return (uintT)f2b(a) | ((uintT)f2b(b) << 16);
}
__device__ __forceinline__ float lo2f(uintT u) {
    return __builtin_bit_cast(float, u << 16);
}
__device__ __forceinline__ float hi2f(uintT u) {
    return __builtin_bit_cast(float, u & 0xffff0000u);
}

// involution permutation for o1's k ordering (store-side packs contiguous k')
__device__ __forceinline__ int sigma(int n) {
    return ((n & 15) << 4) | ((n >> 4) & 7) | ((n & 128) >> 4);
}

__device__ __forceinline__ int bitrev7(int x) {
    return (int)(__brev((unsigned)x) >> 25);
}

// LDS tile index: row r in [0,64), col c in [0,128).
__device__ __forceinline__ int IDX(int r, int c) {
    return (r << 7) + (c ^ (r & 15));
}

__device__ __forceinline__ float2 cmul(float2 a, float2 b) {
    return make_float2(a.x * b.x - a.y * b.y, a.x * b.y + a.y * b.x);
}

// Radix-4 pass fusing radix-2 DIT stages s and s+1 (h = 1<<s).
template <bool INV>
__device__ __forceinline__ void r4pass(float2* D, const float2* __restrict__ twg,
                                       int tid, int s) {
    const int h = 1 << s;
#pragma unroll
    for (int t = 0; t < 2; t++) {
        const int idx = t * 1024 + tid;        // 11 bits
        const int rlo = idx & 15;
        const int gid = (idx >> 4) & 31;
        const int r = ((idx >> 9) << 4) | rlo;
        const int j = gid & (h - 1);
        const int base = ((gid >> s) << (s + 2)) + j;
        float2 t2 = twg[j << (5 - s)];         // stage s+1 twiddle
        float2 t1 = twg[j << (6 - s)];         // stage s twiddle (= t2^2)
        if (INV) { t1.y = -t1.y; t2.y = -t2.y; }
        float2 a = D[IDX(r, base)];
        float2 b = D[IDX(r, base + h)];
        float2 c = D[IDX(r, base + 2 * h)];
        float2 d = D[IDX(r, base + 3 * h)];
        float2 tb = cmul(t1, b), td = cmul(t1, d);
        float2 a1 = make_float2(a.x + tb.x, a.y + tb.y);
        float2 b1 = make_float2(a.x - tb.x, a.y - tb.y);
        float2 c1 = make_float2(c.x + td.x, c.y + td.y);
        float2 d1 = make_float2(c.x - td.x, c.y - td.y);
        float2 tc = cmul(t2, c1), ud = cmul(t2, d1);
        // odd-pair stage-(s+1) twiddle is t2 * (-i) fwd / t2 * (+i) inv
        float2 rot = INV ? make_float2(-ud.y, ud.x) : make_float2(ud.y, -ud.x);
        D[IDX(r, base)]         = make_float2(a1.x + tc.x, a1.y + tc.y);
        D[IDX(r, base + h)]     = make_float2(b1.x + rot.x, b1.y + rot.y);
        D[IDX(r, base + 2 * h)] = make_float2(a1.x - tc.x, a1.y - tc.y);
        D[IDX(r, base + 3 * h)] = make_float2(b1.x - rot.x, b1.y - rot.y);
    }
    __syncthreads();
}

// Final radix-2 stage s=6: pairs (j, j+64), twiddle twg[j].
template <bool INV>
__device__ __forceinline__ void r2final(float2* D, const float2* __restrict__ twg,
                                        int tid) {
#pragma unroll
    for (int t = 0; t < 4; t++) {
        const int idx = t * 1024 + tid;        // 12 bits
        const int rlo = idx & 15;
        const int j = (idx >> 4) & 63;
        const int r = ((idx >> 10) << 4) | rlo;
        float2 w = twg[j];
        if (INV) w.y = -w.y;
        float2 xl = D[IDX(r, j)];
        float2 xh = D[IDX(r, j + 64)];
        const float tr = w.x * xh.x - w.y * xh.y;
        const float ti = w.x * xh.y + w.y * xh.x;
        D[IDX(r, j)]      = make_float2(xl.x + tr, xl.y + ti);
        D[IDX(r, j + 64)] = make_float2(xl.x - tr, xl.y - ti);
    }
    __syncthreads();
}

template <bool INV>
__device__ __forceinline__ void fft64x128(float2* D, const float2* __restrict__ twg,
                                          int tid) {
    r4pass<INV>(D, twg, tid, 0);
    r4pass<INV>(D, twg, tid, 2);
    r4pass<INV>(D, twg, tid, 4);
    r2final<INV>(D, twg, tid);
}

// ======================= Fused forward 2D rFFT ==============================
__global__ __launch_bounds__(1024, 8) void k_fwd2d(const float* __restrict__ x,
                                                   uintT* __restrict__ s0,
                                                   const float2* __restrict__ twg) {
    __shared__ float2 D[8192];           // exactly 64 KB
    const int tid = threadIdx.x;
    const int bc = blockIdx.x;

    // load + pack h-row pairs: Z[hp][w] = x[2hp][w] + i x[2hp+1][w], bitrev w.
    const float* xr = x + (size_t)bc * (NH * NW);
#pragma unroll
    for (int t = 0; t < 2; t++) {
        int i = t * 1024 + tid;          // 2048 tasks x 4 elements
        int hp = i >> 5;
        int w0 = (i & 31) * 4;
        float4 a = *(const float4*)(xr + (size_t)(2 * hp) * NW + w0);
        float4 b = *(const float4*)(xr + (size_t)(2 * hp + 1) * NW + w0);
        D[IDX(hp, bitrev7(w0 + 0))] = make_float2(a.x, b.x);
        D[IDX(hp, bitrev7(w0 + 1))] = make_float2(a.y, b.y);
        D[IDX(hp, bitrev7(w0 + 2))] = make_float2(a.z, b.z);
        D[IDX(hp, bitrev7(w0 + 3))] = make_float2(a.w, b.w);
    }
    __syncthreads();
    fft64x128<false>(D, twg, tid);       // row FFTs (over w)

    // unpack rfft pairs + transpose to [u][h] (h at bitrev positions).
    float2 ra[4], rb[4];
#pragma unroll
    for (int t = 0; t < 4; t++) {
        int i = t * 1024 + tid;          // 4096 tasks
        int hp = i >> 6, j = i & 63;
        ra[t] = D[IDX(hp, j)];
        rb[t] = D[IDX(hp, j ? (128 - j) : 64)];
    }
    __syncthreads();
#pragma unroll
    for (int t = 0; t < 4; t++) {
        int i = t * 1024 + tid;
        int hp = i >> 6, j = i & 63;
        int c0 = bitrev7(2 * hp), c1 = bitrev7(2 * hp + 1);
        float2 a = ra[t], b = rb[t];
        if (j == 0) {                    // rows 0/64 are real: pack as one col
            D[IDX(0, c0)] = make_float2(a.x, b.x);
            D[IDX(0, c1)] = make_float2(a.y, b.y);
        } else {
            // Xe = (a+conj b)/2 -> row 2hp; Xo = (a-conj b)/(2i) -> row 2hp+1
            D[IDX(j, c0)] = make_float2(0.5f * (a.x + b.x), 0.5f * (a.y - b.y));
            D[IDX(j, c1)] = make_float2(0.5f * (a.y + b.y), 0.5f * (b.x - a.x));
        }
    }
    __syncthreads();
    fft64x128<false>(D, twg, tid);       // column FFTs (over h)

    // write packed-bf16 spectrum: v=1..63 direct; v=0 & v=64 from packed row 0.
    uintT* o = s0 + (size_t)bc * NM;
#pragma unroll
    for (int t = 0; t < 8; t++) {
        int i = t * 1024 + tid;          // 8192 tasks x 1 element
        int r = i >> 7, k = i & 127;
        if (r) {
            float2 v = D[IDX(r, k)];
            o[r * 128 + k] = pk2(v.x * INV_N, v.y * INV_N);
        } else {
            float2 ck = D[IDX(0, k)];
            float2 cm = D[IDX(0, (128 - k) & 127)];
            o[k] = pk2(0.5f * (ck.x + cm.x) * INV_N,
                       0.5f * (ck.y - cm.y) * INV_N);
            o[64 * 128 + k] = pk2(0.5f * (ck.y + cm.y) * INV_N,
                                  0.5f * (cm.x - ck.x) * INV_N);
        }
    }
}

// ======================= Fused inverse 2D rFFT ==============================
__global__ __launch_bounds__(1024, 8) void k_inv2d(const uintT* __restrict__ y,
                                                   float* __restrict__ out,
                                                   const float2* __restrict__ twg) {
    __shared__ float2 D[8192];
    const int tid = threadIdx.x;
    const int bc = blockIdx.x;

    // load packed spectrum (4 consecutive k per thread: 16B coalesced reads).
    // v=0/64 Hermitian-symmetrized (== reference's .real drop), packed row 0.
    const uintT* Yb = y + (size_t)bc * NM;
#pragma unroll
    for (int t = 0; t < 2; t++) {
        int i = t * 1024 + tid;          // 2048 tasks x 4 elements
        int r = i >> 5;
        int kq = (i & 31) * 4;
        if (r) {
            uint4 v = *(const uint4*)(Yb + r * 128 + kq);
            D[IDX(r, bitrev7(kq + 0))] = make_float2(lo2f(v.x), hi2f(v.x));
            D[IDX(r, bitrev7(kq + 1))] = make_float2(lo2f(v.y), hi2f(v.y));
            D[IDX(r, bitrev7(kq + 2))] = make_float2(lo2f(v.z), hi2f(v.z));
            D[IDX(r, bitrev7(kq + 3))] = make_float2(lo2f(v.w), hi2f(v.w));
        } else {
#pragma unroll
            for (int dw = 0; dw < 4; dw++) {
                int k = kq + dw;
                int m = (128 - k) & 127;
                uintT a = Yb[k],            am = Yb[m];
                uintT b = Yb[64 * 128 + k], bm = Yb[64 * 128 + m];
                float h0x = 0.5f * (lo2f(a) + lo2f(am)), h0y = 0.5f * (hi2f(a) - hi2f(am));
                float h6x = 0.5f * (lo2f(b) + lo2f(bm)), h6y = 0.5f * (hi2f(b) - hi2f(bm));
                D[IDX(0, bitrev7(k))] = make_float2(h0x - h6y, h0y + h6x);
            }
        }
    }
    __syncthreads();
    fft64x128<true>(D, twg, tid);        // column iFFTs (k -> h)

    // transpose + Hermitian-extend to Z[hp][u] (u at bitrev positions).
    float2 ra[4], rb[4];
#pragma unroll
    for (int t = 0; t < 4; t++) {
        int i = t * 1024 + tid;          // 12 bits
        int hp = (i & 15) | (((i >> 10) & 3) << 4);
        int j  = ((i >> 4) & 3) | (((i >> 6) & 15) << 2);
        ra[t] = D[IDX(j, 2 * hp)];
        rb[t] = D[IDX(j, 2 * hp + 1)];
    }
    __syncthreads();
#pragma unroll
    for (int t = 0; t < 4; t++) {
        int i = t * 1024 + tid;
        int hp = (i & 15) | (((i >> 10) & 3) << 4);
        int j  = ((i >> 4) & 3) | (((i >> 6) & 15) << 2);
        float2 e = ra[t], f = rb[t];
        if (j == 0) {                    // row 0 held (ReX_h[0], ReX_h[64])
            D[IDX(hp, bitrev7(0))]  = make_float2(e.x, f.x);
            D[IDX(hp, bitrev7(64))] = make_float2(e.y, f.y);
        } else {
            // Z[hp][j] = e + i f ;  Z[hp][128-j] = conj(e) + i conj(f)
            D[IDX(hp, bitrev7(j))]       = make_float2(e.x - f.y, e.y + f.x);
            D[IDX(hp, bitrev7(128 - j))] = make_float2(e.x + f.y, f.x - e.y);
        }
    }
    __syncthreads();
    fft64x128<true>(D, twg, tid);        // row iFFTs (u -> w)

    // output: z[hp][w] = x[2hp][w] + i x[2hp+1][w].
    float* ob = out + (size_t)bc * (NH * NW);
#pragma unroll
    for (int t = 0; t < 8; t++) {
        int i = t * 1024 + tid;          // 8192 tasks x 1 element
        int hp = i >> 7, w = i & 127;
        float2 v = D[IDX(hp, w)];
        ob[(size_t)(2 * hp) * NW + w]     = v.x * INV_N;
        ob[(size_t)(2 * hp + 1) * NW + w] = v.y * INV_N;
    }
}

// ======================= Weight prep + twiddle table ========================
__global__ __launch_bounds__(256) void k_prep_w(const float* __restrict__ w1,
                                                const float* __restrict__ w2,
                                                ushortT* __restrict__ Wp,
                                                float2* __restrict__ twg) {
    if (blockIdx.x == 0 && threadIdx.x < 64) {
        float s, c;
        sincosf(-3.14159265358979323846f * (float)threadIdx.x / 64.0f, &s, &c);
        twg[threadIdx.x] = make_float2(c, s);
    }
    int idx = blockIdx.x * 256 + threadIdx.x;      // 2*4*256*256
    int k = idx & 255;
    int n = (idx >> 8) & 255;
    int g = (idx >> 16) & 3;
    int l = idx >> 18;
    const float* w = l ? w2 : w1;
    int kk = l ? sigma(k) : k;
    int ki = kk & 127, no = n & 127;
    float val;
    if (kk < 128) {
        val = (n < 128) ? w[((0 * NG + g) * ND + ki) * ND + no]
                        : w[((1 * NG + g) * ND + ki) * ND + no];
    } else {
        val = (n < 128) ? -w[((1 * NG + g) * ND + ki) * ND + no]
                        :  w[((0 * NG + g) * ND + ki) * ND + no];
    }
    Wp[((size_t)(l * NG + g) * 256 + n) * 256 + k] = f2b(val);
}

// ======================= Fused GEMM1 + GEMM2 (bf16 spectrum I/O) ============
__global__ __launch_bounds__(512, 4) void k_gemm_fused(uintT* __restrict__ S,
                                                       const ushortT* __restrict__ Wp,
                                                       const float* __restrict__ B1,
                                                       const float* __restrict__ B2) {
    __shared__ unsigned char smem[65536];
    ushortT* Alds = (ushortT*)smem;
    ushortT* o1l  = (ushortT*)smem;
    float2*  E    = (float2*)smem;

    const int tid = threadIdx.x;
    const int mt = blockIdx.x, bk = blockIdx.y;
    const int g = bk & 3;
    const int m0 = mt * 128;
    const int lane = tid & 63, wid = tid >> 6;
    const int col = lane & 15, quad = lane >> 4;
    const int wm = wid & 1, wn = wid >> 1;          // wn in [0,4)

    uintT* Ab = S + (size_t)(bk * ND) * NM + m0;
    const ushortT* Wg1 = Wp + (size_t)g * 65536;
    const ushortT* Wg2 = Wp + (size_t)(NG + g) * 65536;

    f32x4 acc[4][4];
#pragma unroll
    for (int i = 0; i < 4; i++)
#pragma unroll
        for (int j = 0; j < 4; j++) acc[i][j] = f32x4{0.f, 0.f, 0.f, 0.f};

    // ---- phase 1: gemm1. A staged (already bf16: pure repack, no cvt);
    //      W1 fragments straight from L2.
    for (int s = 0; s < 2; s++) {
        const int cs = s * 64;
        __syncthreads();
        {
            const int oct = tid >> 6;               // 0..7
            const int mp = (tid & 63) * 2;          // 0..126
            union { ushortT u[8]; uint4 v; } re0, re1, im0, im1;
#pragma unroll
            for (int j = 0; j < 8; j++) {
                const uint2 v = *(const uint2*)(Ab + (size_t)(cs + oct * 8 + j) * NM + mp);
                re0.u[j] = (ushortT)(v.x & 0xffffu); im0.u[j] = (ushortT)(v.x >> 16);
                re1.u[j] = (ushortT)(v.y & 0xffffu); im1.u[j] = (ushortT)(v.y >> 16);
            }
            *(uint4*)&Alds[(oct * 128 + mp) * 8] = re0.v;
            *(uint4*)&Alds[(oct * 128 + mp + 1) * 8] = re1.v;
            *(uint4*)&Alds[((8 + oct) * 128 + mp) * 8] = im0.v;
            *(uint4*)&Alds[((8 + oct) * 128 + mp + 1) * 8] = im1.v;
        }
        __syncthreads();
#pragma unroll
        for (int h = 0; h < 2; h++) {
            const int kbase = h * 128 + cs;
#pragma unroll
            for (int ksl = 0; ksl < 2; ksl++) {
                bf16x8 a[4];
#pragma unroll
                for (int mi = 0; mi < 4; mi++)
                    a[mi] = *(const bf16x8*)&Alds[((h * 8 + ksl * 4 + quad) * 128
                                                   + wm * 64 + mi * 16 + col) * 8];
#pragma unroll
                for (int ni = 0; ni < 4; ni++) {
                    const int n = wn * 64 + ni * 16 + col;
                    bf16x8 b = *(const bf16x8*)(Wg1 + (size_t)n * 256 + kbase
                                                + (ksl * 4 + quad) * 8);
#pragma unroll
                    for (int mi = 0; mi < 4; mi++)
                        acc[mi][ni] = __builtin_amdgcn_mfma_f32_16x16x32_bf16(
                            a[mi], b, acc[mi][ni], 0, 0, 0);
                }
            }
        }
    }

    // ---- phase 2: bias + relu -> bf16 o1 tile in LDS.
    float bR[4];
#pragma unroll
    for (int ni = 0; ni < 4; ni++) {
        const int n = wn * 64 + ni * 16 + col;
        bR[ni] = (n < 128) ? B1[g * ND + n] : B1[512 + g * ND + (n - 128)];
    }
    __syncthreads();                                // all Alds reads done
    {
        const int kq = col * 2 + (wn >> 1);
        const int xo = col & 7;                     // (kq>>1)&7
        const int pos = (wn & 1) * 4;
#pragma unroll
        for (int mi = 0; mi < 4; mi++)
#pragma unroll
            for (int r = 0; r < 4; r++) {
                const int ml = wm * 64 + mi * 16 + quad * 4 + r;
                union { ushortT u[4]; uint2 v; } pk;
#pragma unroll
                for (int ni = 0; ni < 4; ni++)
                    pk.u[ni] = f2b(fmaxf(acc[mi][ni][r] + bR[ni], 0.f));
                *(uint2*)&o1l[(kq * 128 + (ml ^ xo)) * 8 + pos] = pk.v;
            }
    }
    __syncthreads();

    // ---- phase 3: gemm2. A from o1 LDS; W2 fragments straight from L2.
#pragma unroll
    for (int i = 0; i < 4; i++)
#pragma unroll
        for (int j = 0; j < 4; j++) acc[i][j] = f32x4{0.f, 0.f, 0.f, 0.f};

#pragma unroll
    for (int kqs = 0; kqs < 8; kqs++) {
        const int kq = kqs * 4 + quad;
        const int xo = (kq >> 1) & 7;
        bf16x8 a[4];
#pragma unroll
        for (int mi = 0; mi < 4; mi++)
            a[mi] = *(const bf16x8*)&o1l[(kq * 128 + ((wm * 64 + mi * 16 + col) ^ xo)) * 8];
#pragma unroll
        for (int ni = 0; ni < 4; ni++) {
            const int n = wn * 64 + ni * 16 + col;
            bf16x8 b = *(const bf16x8*)(Wg2 + (size_t)n * 256 + (size_t)kq * 8);
#pragma unroll
            for (int mi = 0; mi < 4; mi++)
                acc[mi][ni] = __builtin_amdgcn_mfma_f32_16x16x32_bf16(
                    a[mi], b, acc[mi][ni], 0, 0, 0);
        }
    }

    // ---- epilogue: pair (real, imag) across waves via LDS, *origin, RMW.
    const int ri = wn >> 1;                          // 0 = real half, 1 = imag
#pragma unroll
    for (int p = 0; p < 4; p++) {
        __syncthreads();
        if ((wn & 1) == (p >> 1)) {
#pragma unroll
            for (int q2 = 0; q2 < 2; q2++) {
                const int nic = (p & 1) * 2 + q2;
                const int ch_l = q2 * 16 + col;
                const int ch = p * 32 + ch_l;
                const float bias = ri ? B2[512 + g * ND + ch] : B2[g * ND + ch];
#pragma unroll
                for (int mi = 0; mi < 4; mi++)
#pragma unroll
                    for (int r = 0; r < 4; r++) {
                        const int ml = wm * 64 + mi * 16 + quad * 4 + r;
                        ((float*)&E[ch_l * 129 + ml])[ri] = acc[mi][nic][r] + bias;
                    }
            }
        }
        __syncthreads();
#pragma unroll
        for (int j = 0; j < 8; j++) {
            const int idx = j * 512 + tid;
            const int ch_l = idx >> 7, ml = idx & 127;
            const float2 v = E[ch_l * 129 + ml];
            uintT* Yp = Ab + (size_t)(p * 32 + ch_l) * NM + ml;
            const uintT o = *Yp;
            const float ox = lo2f(o), oy = hi2f(o);
            *Yp = pk2(v.x * ox - v.y * oy, v.x * oy + v.y * ox);
        }
    }
}

// ======================= launch =============================================
extern "C" void kernel_launch(void* const* d_in, const int* in_sizes, int n_in,
                              void* d_out, int out_size, void* d_ws, size_t ws_size,
                              hipStream_t stream) {
    (void)in_sizes; (void)n_in; (void)out_size; (void)ws_size;
    const float* x  = (const float*)d_in[0];
    const float* w1 = (const float*)d_in[1];
    const float* w2 = (const float*)d_in[2];
    const float* b1 = (const float*)d_in[3];
    const float* b2 = (const float*)d_in[4];
    float* outp = (float*)d_out;

    uintT* buf1 = (uintT*)d_ws;                          // 136,314,880 B
    char*  ws2  = (char*)d_ws + (size_t)NB * NC * NM * sizeof(float2);
    ushortT* Wp  = (ushortT*)(ws2 + (size_t)144 * 1024 * 1024);   // 1 MB
    float2* twg  = (float2*)((char*)Wp + (size_t)1048576);        // 512 B

    k_prep_w<<<dim3(2048), 256, 0, stream>>>(w1, w2, Wp, twg);
    k_fwd2d<<<dim3(NB * NC), 1024, 0, stream>>>(x, buf1, twg);
    k_gemm_fused<<<dim3(NM / 128, NB * NG), 512, 0, stream>>>(buf1, Wp, b1, b2);
    k_inv2d<<<dim3(NB * NC), 1024, 0, stream>>>(buf1, outp, twg);
}